// Round 11
// baseline (41.293 us; speedup 1.0000x reference)
//
#include <hip/hip_runtime.h>
#include <hip/hip_fp16.h>

// DCNv2: B=2, CIN=COUT=64, H=W=128, DG=8, cpg=8, 3x3 s1 p1 d1
constexpr int BB = 2;
constexpr int CINc = 64;
constexpr int HWc = 128 * 128;
constexpr int OCOFFc = 216;   // DG*3*9 offset-conv channels
constexpr int XP = 130;       // padded spatial dim (halo of 1)

// workspace layout (bytes)
constexpr size_t XT_BYTES  = (size_t)BB * 8 * XP * XP * 8 * 2;   // per-(b,dg) planes, 16B/px
constexpr size_t WB1_OFF   = XT_BYTES;
constexpr size_t WB1_BYTES = (size_t)9 * 8 * 256 * 8 * 2;        // offset W [tap][cgrp][oc256][8ci] fp16
constexpr size_t WM_OFF    = WB1_OFF + WB1_BYTES;
constexpr size_t WM_BYTES  = (size_t)8 * 12 * 64 * 8 * 2;        // main W [dg][tap12][oc][8c] fp16
constexpr size_t WS_NEEDED = WM_OFF + WM_BYTES;                  // ~4.7 MB

typedef _Float16 f16x8 __attribute__((ext_vector_type(8)));
typedef float    f32x4 __attribute__((ext_vector_type(4)));

// ---------- K0: fused prep: x->planes, weight transforms, halo zero ----------
__global__ void prep_all(const float* __restrict__ x, const float* __restrict__ w_off,
                         const float* __restrict__ weight,
                         __half* __restrict__ xT, __half* __restrict__ wB1,
                         __half* __restrict__ wM) {
    int bid = blockIdx.x;
    if (bid < 1024) {
        int site = bid * 256 + threadIdx.x;      // B*8*HW = 262144
        int pix = site & (HWc - 1);
        int bdg = site >> 14;
        int dg = bdg & 7, b = bdg >> 3;
        int y = pix >> 7, xc = pix & 127;
        const float* xp = x + (size_t)(b * CINc + dg * 8) * HWc + pix;
        __half2 h0 = __halves2half2(__float2half(xp[0 * HWc]), __float2half(xp[1 * HWc]));
        __half2 h1 = __halves2half2(__float2half(xp[2 * HWc]), __float2half(xp[3 * HWc]));
        __half2 h2 = __halves2half2(__float2half(xp[4 * HWc]), __float2half(xp[5 * HWc]));
        __half2 h3 = __halves2half2(__float2half(xp[6 * HWc]), __float2half(xp[7 * HWc]));
        __half2* o = reinterpret_cast<__half2*>(
            xT + (((size_t)(b * 8 + dg) * XP + y + 1) * XP + xc + 1) * 8);
        o[0] = h0; o[1] = h1; o[2] = h2; o[3] = h3;
        return;
    }
    int idx = (bid - 1024) * 256 + threadIdx.x;
    if (idx < 9 * 8 * 256 * 8) {
        // wB1[tap][cgrp][oc][ci]: fragment-major, coalesced for direct global B-reads
        int ci = idx & 7;
        int oc = (idx >> 3) & 255;
        int c  = (idx >> 11) & 7;
        int tap = idx >> 14;
        float v = (oc < OCOFFc) ? w_off[oc * 576 + (c * 8 + ci) * 9 + tap] : 0.f;
        wB1[idx] = __float2half(v);
    } else if (idx < 9 * 8 * 256 * 8 + 8 * 12 * 64 * 8) {
        int j = idx - 9 * 8 * 256 * 8;       // wM[dg][tap12][oc][c]
        int c = j & 7;
        int oc = (j >> 3) & 63;
        int tg = j >> 9;                      // dg*12 + tap
        int tap = tg % 12;
        int dg = tg / 12;
        float v = (tap < 9) ? weight[oc * 576 + (dg * 8 + c) * 9 + tap] : 0.f;
        wM[j] = __float2half(v);
    } else {
        int j2 = idx - (9 * 8 * 256 * 8 + 8 * 12 * 64 * 8);   // halo zero: 16 planes x 516 px
        if (j2 < 16 * 516) {
            int plane = j2 / 516;
            int p = j2 - plane * 516;
            int y, xx;
            if (p < 130)      { y = 0;           xx = p; }
            else if (p < 260) { y = 129;         xx = p - 130; }
            else if (p < 388) { y = 1 + p - 260; xx = 0; }
            else              { y = 1 + p - 388; xx = 129; }
            uint4 z = {0u, 0u, 0u, 0u};
            *reinterpret_cast<uint4*>(xT + (((size_t)plane * XP + y) * XP + xx) * 8) = z;
        }
    }
}

// Phase B: compute blend weights + fetch 12 corners for group DG.
// Corners served from LDS patch when in-range (always, for this data);
// per-corner global fallback keeps arbitrary-offset correctness.
#define DCN_ISSUE(DG, G, W)                                                    \
  {                                                                            \
    const int dg_ = (DG);                                                      \
    const __half* xb_ = xT + (size_t)(b * 8 + dg_) * XP * XP * 8;              \
    _Pragma("unroll")                                                          \
    for (int s_ = 0; s_ < 3; ++s_) {                                           \
      const int kg_ = s_ * 4 + lh;                                             \
      if (kg_ < 9) {                                                           \
        const int r3_ = (dg_ * 9 + kg_) * 3;                                   \
        float oy_ = __half2float(offsb[r3_ * 132 + px]);                       \
        float ox_ = __half2float(offsb[(r3_ + 1) * 132 + px]);                 \
        float mk_ = __half2float(offsb[(r3_ + 2) * 132 + px]);                 \
        const int ki_ = kg_ / 3, kj_ = kg_ - ki_ * 3;                          \
        float sy_ = oy_ + (float)(gy - 1 + ki_);                               \
        float sx_ = ox_ + (float)(gx - 1 + kj_);                               \
        float y0f_ = floorf(sy_), x0f_ = floorf(sx_);                          \
        int iy0_ = (int)y0f_, ix0_ = (int)x0f_;                                \
        float ly_ = sy_ - y0f_, lx_ = sx_ - x0f_;                              \
        float hy_ = 1.f - ly_, hx_ = 1.f - lx_;                                \
        float vy0_ = ((unsigned)iy0_ < 128u) ? 1.f : 0.f;                      \
        float vy1_ = ((unsigned)(iy0_ + 1) < 128u) ? 1.f : 0.f;                \
        float vx0_ = ((unsigned)ix0_ < 128u) ? 1.f : 0.f;                      \
        float vx1_ = ((unsigned)(ix0_ + 1) < 128u) ? 1.f : 0.f;                \
        W[s_ * 4 + 0] = hy_ * hx_ * vy0_ * vx0_ * mk_;                         \
        W[s_ * 4 + 1] = hy_ * lx_ * vy0_ * vx1_ * mk_;                         \
        W[s_ * 4 + 2] = ly_ * hx_ * vy1_ * vx0_ * mk_;                         \
        W[s_ * 4 + 3] = ly_ * lx_ * vy1_ * vx1_ * mk_;                         \
        int y0c_ = min(max(iy0_, 0), 127), y1c_ = min(max(iy0_ + 1, 0), 127);  \
        int x0c_ = min(max(ix0_, 0), 127), x1c_ = min(max(ix0_ + 1, 0), 127);  \
        const int pr0_ = y0c_ + 1 - prow0, pr1_ = y1c_ + 1 - prow0;            \
        const int pc0_ = x0c_ + 1 - pcol0, pc1_ = x1c_ + 1 - pcol0;            \
        const int sl0_ = dg_ ^ (pc0_ & 7), sl1_ = dg_ ^ (pc1_ & 7);            \
        if ((unsigned)pr0_ < 14u && (unsigned)pc0_ < 22u)                      \
          G[s_ * 4 + 0] = *reinterpret_cast<const float4*>(patch + ((pr0_ * 22 + pc0_) * 8 + sl0_) * 8); \
        else                                                                   \
          G[s_ * 4 + 0] = *reinterpret_cast<const float4*>(xb_ + ((size_t)(y0c_ + 1) * XP + x0c_ + 1) * 8); \
        if ((unsigned)pr0_ < 14u && (unsigned)pc1_ < 22u)                      \
          G[s_ * 4 + 1] = *reinterpret_cast<const float4*>(patch + ((pr0_ * 22 + pc1_) * 8 + sl1_) * 8); \
        else                                                                   \
          G[s_ * 4 + 1] = *reinterpret_cast<const float4*>(xb_ + ((size_t)(y0c_ + 1) * XP + x1c_ + 1) * 8); \
        if ((unsigned)pr1_ < 14u && (unsigned)pc0_ < 22u)                      \
          G[s_ * 4 + 2] = *reinterpret_cast<const float4*>(patch + ((pr1_ * 22 + pc0_) * 8 + sl0_) * 8); \
        else                                                                   \
          G[s_ * 4 + 2] = *reinterpret_cast<const float4*>(xb_ + ((size_t)(y1c_ + 1) * XP + x0c_ + 1) * 8); \
        if ((unsigned)pr1_ < 14u && (unsigned)pc1_ < 22u)                      \
          G[s_ * 4 + 3] = *reinterpret_cast<const float4*>(patch + ((pr1_ * 22 + pc1_) * 8 + sl1_) * 8); \
        else                                                                   \
          G[s_ * 4 + 3] = *reinterpret_cast<const float4*>(xb_ + ((size_t)(y1c_ + 1) * XP + x1c_ + 1) * 8); \
      } else {                                                                 \
        const float4 z4_ = {0.f, 0.f, 0.f, 0.f};                               \
        W[s_ * 4 + 0] = 0.f; W[s_ * 4 + 1] = 0.f;                              \
        W[s_ * 4 + 2] = 0.f; W[s_ * 4 + 3] = 0.f;                              \
        G[s_ * 4 + 0] = z4_; G[s_ * 4 + 1] = z4_;                              \
        G[s_ * 4 + 2] = z4_; G[s_ * 4 + 3] = z4_;                              \
      }                                                                        \
    }                                                                          \
  }

// Phase B: blend staged corners -> af fragments, then 12 MFMAs for group DG
#define DCN_CONSUME(DG, G, W)                                                  \
  {                                                                            \
    const int dg_ = (DG);                                                      \
    f16x8 bf_[12];                                                             \
    _Pragma("unroll")                                                          \
    for (int s_ = 0; s_ < 3; ++s_)                                             \
      _Pragma("unroll")                                                        \
      for (int n_ = 0; n_ < 4; ++n_)                                           \
        bf_[s_ * 4 + n_] = *reinterpret_cast<const f16x8*>(                    \
            wM + (size_t)((dg_ * 12 + s_ * 4 + lh) * 64 + n_ * 16 + l15) * 8); \
    f16x8 af_[3];                                                              \
    _Pragma("unroll")                                                          \
    for (int s_ = 0; s_ < 3; ++s_) {                                           \
      __half2 W00_ = __float2half2_rn(W[s_ * 4 + 0]);                          \
      __half2 W01_ = __float2half2_rn(W[s_ * 4 + 1]);                          \
      __half2 W10_ = __float2half2_rn(W[s_ * 4 + 2]);                          \
      __half2 W11_ = __float2half2_rn(W[s_ * 4 + 3]);                          \
      const __half2* a00_ = reinterpret_cast<const __half2*>(&G[s_ * 4 + 0]);  \
      const __half2* a01_ = reinterpret_cast<const __half2*>(&G[s_ * 4 + 1]);  \
      const __half2* a10_ = reinterpret_cast<const __half2*>(&G[s_ * 4 + 2]);  \
      const __half2* a11_ = reinterpret_cast<const __half2*>(&G[s_ * 4 + 3]);  \
      __align__(16) __half2 rr_[4];                                            \
      _Pragma("unroll")                                                        \
      for (int cc_ = 0; cc_ < 4; ++cc_)                                        \
        rr_[cc_] = __hfma2(a00_[cc_], W00_,                                    \
                   __hfma2(a01_[cc_], W01_,                                    \
                   __hfma2(a10_[cc_], W10_, __hmul2(a11_[cc_], W11_))));       \
      af_[s_] = *reinterpret_cast<const f16x8*>(rr_);                          \
    }                                                                          \
    _Pragma("unroll")                                                          \
    for (int s_ = 0; s_ < 3; ++s_)                                             \
      _Pragma("unroll")                                                        \
      for (int n_ = 0; n_ < 4; ++n_)                                           \
        acc2[n_] = __builtin_amdgcn_mfma_f32_16x16x32_f16(                     \
            af_[s_], bf_[s_ * 4 + n_], acc2[n_], 0, 0, 0);                     \
  }

// ---------- Fused DCN: 128px tile, 512 thr, grid 256, XCD swizzle ----------
// Phase A: offset conv, B direct from global (L2), no barriers (2 total in kernel).
// Phase B: bilinear corners served from the 14x22x64ch LDS patch (global fallback),
//          dg-pipelined register staging.
__global__ __launch_bounds__(512, 2) void dcn_fused_k(
        const __half* __restrict__ xT, const __half* __restrict__ wB1,
        const float* __restrict__ cob, const __half* __restrict__ wM,
        const float* __restrict__ bias, float* __restrict__ out) {
    __shared__ __half patch[14 * 22 * 64];   // 39424 B: [pr14][pc22][sl8][8ch]
    __shared__ __half offsb[216 * 132];      // 57024 B: [(dg*9+k)*3+comp][px128 pad132]
    const int tid = threadIdx.x;
    // XCD-aware swizzle: each XCD gets 32 consecutive vids = 4 contiguous row-bands
    const int fid = blockIdx.x + (blockIdx.y << 3) + (blockIdx.z << 7);
    const int vid = ((fid & 7) << 5) + (fid >> 3);
    const int bx = vid & 7;               // 0..7   (16 px wide)
    const int by = (vid >> 3) & 15;       // 0..15  (8 px tall)
    const int b  = vid >> 7;

    const int prow0 = by * 8 - 2;         // padded row of patch row 0
    const int pcol0 = bx * 16 - 2;        // padded col of patch col 0

    // ---- stage 14x22 padded-coord patch (clamped; slot = dg^(pc&7)) ----
    #pragma unroll
    for (int it = 0; it < 5; ++it) {
        int idx = tid + it * 512;
        if (idx < 2464) {
            int pr = idx / 176;                  // 176 = 22 cols * 8 slots
            int rem = idx - pr * 176;
            int pc = rem >> 3, sl = rem & 7;
            int dg = sl ^ (pc & 7);
            int srow = min(max(prow0 + pr, 0), 129);
            int scol = min(max(pcol0 + pc, 0), 129);
            float4 v = *reinterpret_cast<const float4*>(
                xT + (((size_t)(b * 8 + dg) * XP + srow) * XP + scol) * 8);
            *reinterpret_cast<float4*>(patch + idx * 8) = v;
        }
    }
    __syncthreads();   // barrier 1: patch ready (read-only hereafter)

    const int lane = tid & 63;
    const int wid = tid >> 6;
    const int l15 = lane & 15, lh = lane >> 4;

    {   // ---- Phase A: 9-tap implicit GEMM, NO barriers; bf direct from global ----
        const int wr = wid & 1;            // px half (4 image rows)
        const int wc = wid >> 1;           // oc quarter (64 of 256)
        f32x4 acc[4][4];
        const f32x4 zero = {0.f, 0.f, 0.f, 0.f};
        #pragma unroll
        for (int ty = 0; ty < 4; ++ty)
            #pragma unroll
            for (int ot = 0; ot < 4; ++ot) acc[ty][ot] = zero;

        #pragma unroll 3
        for (int tap = 0; tap < 9; ++tap) {
            const int r = tap / 3, s = tap - r * 3;
            const int j = l15 + s;                    // patch col - 2 (old coords)
            #pragma unroll
            for (int h = 0; h < 2; ++h) {
                const int c = h * 4 + lh;             // cin group 0..7
                const int sl = c ^ ((j + 2) & 7);
                f16x8 af[4], bf[4];
                #pragma unroll
                for (int ot = 0; ot < 4; ++ot) {
                    int oc = wc * 64 + ot * 16 + l15;
                    bf[ot] = *reinterpret_cast<const f16x8*>(
                        wB1 + (size_t)(((tap * 8 + c) * 256 + oc)) * 8);
                }
                #pragma unroll
                for (int ty = 0; ty < 4; ++ty) {
                    int row = wr * 4 + ty + r;
                    af[ty] = *reinterpret_cast<const f16x8*>(
                        patch + (((row + 2) * 22 + (j + 2)) * 8 + sl) * 8);
                }
                #pragma unroll
                for (int ty = 0; ty < 4; ++ty)
                    #pragma unroll
                    for (int ot = 0; ot < 4; ++ot)
                        acc[ty][ot] = __builtin_amdgcn_mfma_f32_16x16x32_f16(
                            af[ty], bf[ot], acc[ty][ot], 0, 0, 0);
            }
        }

        // ---- Phase A epilogue -> offsb (LDS). D: oc=l15-col, x-offset=lh*4+reg ----
        #pragma unroll
        for (int ot = 0; ot < 4; ++ot) {
            int oc = wc * 64 + ot * 16 + l15;
            if (oc < OCOFFc) {
                float bi = cob[oc];
                bool sig = (oc >= 144);
                int dg, k, comp;
                if (oc < 144) { dg = oc / 18; int rem = oc - dg * 18; k = rem >> 1; comp = rem & 1; }
                else          { int mm = oc - 144; dg = mm / 9; k = mm - dg * 9; comp = 2; }
                int r3 = (dg * 9 + k) * 3 + comp;
                #pragma unroll
                for (int ty = 0; ty < 4; ++ty) {
                    int px = (wr * 4 + ty) * 16 + lh * 4;
                    float v0 = acc[ty][ot][0] + bi, v1 = acc[ty][ot][1] + bi;
                    float v2 = acc[ty][ot][2] + bi, v3 = acc[ty][ot][3] + bi;
                    if (sig) {
                        v0 = 1.f / (1.f + __expf(-v0)); v1 = 1.f / (1.f + __expf(-v1));
                        v2 = 1.f / (1.f + __expf(-v2)); v3 = 1.f / (1.f + __expf(-v3));
                    }
                    __half2* d = reinterpret_cast<__half2*>(&offsb[r3 * 132 + px]);
                    d[0] = __halves2half2(__float2half(v0), __float2half(v1));
                    d[1] = __halves2half2(__float2half(v2), __float2half(v3));
                }
            }
        }
    }
    __syncthreads();   // barrier 2: offsb complete

    // ---- Phase B: wave = image row; dg-pipelined, LDS-patch-served sampling ----
    const int px = wid * 16 + l15;    // offsb px index
    const int gy = by * 8 + wid;
    const int gx = bx * 16 + l15;

    f32x4 acc2[4];
    const f32x4 zero2 = {0.f, 0.f, 0.f, 0.f};
    #pragma unroll
    for (int n = 0; n < 4; ++n) acc2[n] = zero2;

    float4 gA[12]; float wA[12];
    float4 gB[12]; float wB[12];

    DCN_ISSUE(0, gA, wA);
    #pragma unroll 1
    for (int d = 0; d < 8; d += 2) {
        DCN_ISSUE(d + 1, gB, wB);
        DCN_CONSUME(d, gA, wA);
        if (d + 2 < 8) DCN_ISSUE(d + 2, gA, wA);
        DCN_CONSUME(d + 1, gB, wB);
    }

    // ---- store: D row -> x-offset (lh*4+reg), col -> oc (n*16+l15) ----
    #pragma unroll
    for (int n = 0; n < 4; ++n) {
        int oc = n * 16 + l15;
        float bi = bias[oc];
        float4 v = make_float4(acc2[n][0] + bi, acc2[n][1] + bi,
                               acc2[n][2] + bi, acc2[n][3] + bi);
        *reinterpret_cast<float4*>(
            out + (size_t)(b * 64 + oc) * HWc + gy * 128 + bx * 16 + lh * 4) = v;
    }
}

extern "C" void kernel_launch(void* const* d_in, const int* in_sizes, int n_in,
                              void* d_out, int out_size, void* d_ws, size_t ws_size,
                              hipStream_t stream) {
    const float* x      = (const float*)d_in[0];
    const float* w_off  = (const float*)d_in[1];
    const float* cob    = (const float*)d_in[2];
    const float* weight = (const float*)d_in[3];
    const float* bias   = (const float*)d_in[4];
    float* out = (float*)d_out;
    if (ws_size < WS_NEEDED) return;

    char* ws = (char*)d_ws;
    __half* xT  = (__half*)ws;
    __half* wB1 = (__half*)(ws + WB1_OFF);
    __half* wM  = (__half*)(ws + WM_OFF);

    prep_all<<<1825, 256, 0, stream>>>(x, w_off, weight, xT, wB1, wM);
    dcn_fused_k<<<dim3(8, 16, 2), 512, 0, stream>>>(xT, wB1, cob, wM, bias, out);
}